// Round 2
// baseline (33490.894 us; speedup 1.0000x reference)
//
#include <hip/hip_runtime.h>
#include <hip/hip_fp16.h>

// LSTM: B=32, T=4096, D=256, H=256, gates=1024 (i,g,f,o), HORIZON=24
// Pipeline: prep_x (f32->bf16) ; prep_w (WxT bf16 for xproj, WhA f16 remapped for scan MFMA) ;
//           xproj MFMA GEMM -> gates_x f16 G[t][b][1024 remapped] (bias + forget+1 folded) ;
//           scan: 8 blocks (2 batch-groups x 4 j-quarters) x 256 thr.
//             Each block: A-frags (its 256 gate rows x 256 k) resident in VGPRs,
//             gates = Wh @ H via mfma_f32_16x16x32_f16 (B = 16 batches, zero waste),
//             i/g/f/o of each j in ONE wave -> h computed in-register.
//             Cross-block h exchange: double-buffered global hx + per-wave release counters.
//           head: two tiny FCs.

#define T_STEPS 4096

typedef short short8 __attribute__((ext_vector_type(8)));
typedef _Float16 half8 __attribute__((ext_vector_type(8)));
typedef float f32x4 __attribute__((ext_vector_type(4)));
typedef unsigned long long ull2 __attribute__((ext_vector_type(2)));

__device__ inline unsigned short f32_to_bf16(float f) {
  unsigned int u = __builtin_bit_cast(unsigned int, f);
  u = u + 0x7fffu + ((u >> 16) & 1u);   // RNE
  return (unsigned short)(u >> 16);
}

// ---------------- prep: x f32 -> bf16 ----------------
__global__ void k_prep_x(const float4* __restrict__ x, unsigned short* __restrict__ xbf, int n4) {
  int i = blockIdx.x * blockDim.x + threadIdx.x;
  if (i >= n4) return;
  float4 v = x[i];
  ushort4 o;
  o.x = f32_to_bf16(v.x); o.y = f32_to_bf16(v.y);
  o.z = f32_to_bf16(v.z); o.w = f32_to_bf16(v.w);
  ((ushort4*)xbf)[i] = o;
}

// ---------------- prep: weights ----------------
// WxT[n][k] = bf16(W_lstm[k][n]) for k<256 (xproj B-frags contiguous)
// WhA[srow][k] = f16(W_lstm[256+k][c]) with srow = qt*256 + gate*64 + jl for c = gate*256 + qt*64 + jl
//   (row remap so scan block qt owns i,g,f,o of its 64 j's contiguously)
__global__ void k_prep_w(const float* __restrict__ W, unsigned short* __restrict__ WxT,
                         _Float16* __restrict__ WhA) {
  int i = blockIdx.x * blockDim.x + threadIdx.x;
  if (i < 256 * 1024) {
    int n = i >> 8, k = i & 255;
    WxT[i] = f32_to_bf16(W[k * 1024 + n]);
  } else {
    int j = i - 256 * 1024;          // j in [0, 262144)
    int srow = j >> 8, k = j & 255;
    int qt = srow >> 8, rem = srow & 255, gate = rem >> 6, jl = rem & 63;
    int c = gate * 256 + qt * 64 + jl;
    WhA[j] = (_Float16)W[(256 + k) * 1024 + c];
  }
}

// ---------------- xproj: gates_x = x @ Wx + b (+1 on f-gate) ----------------
// M=131072, N=1024, K=256. Output layout: G[t][b][srow] f16 (srow = scan row remap).
__global__ __launch_bounds__(256) void k_xproj(const unsigned short* __restrict__ A,
                                               const unsigned short* __restrict__ BT,
                                               const float* __restrict__ bias,
                                               __half* __restrict__ G) {
  int bm = blockIdx.x * 64;
  int bn = blockIdx.y * 64;
  int lane = threadIdx.x & 63, wave = threadIdx.x >> 6;
  int wm = (wave & 1) * 32, wn = (wave >> 1) * 32;
  int q = lane >> 4, l16 = lane & 15;

  f32x4 acc[2][2] = {};
  const unsigned short* Ab = A + (size_t)(bm + wm + l16) * 256 + q * 8;
  const unsigned short* Bb = BT + (size_t)(bn + wn + l16) * 256 + q * 8;

#pragma unroll
  for (int kk = 0; kk < 8; ++kk) {
    short8 a0 = *(const short8*)(Ab + kk * 32);
    short8 a1 = *(const short8*)(Ab + 16 * 256 + kk * 32);
    short8 b0 = *(const short8*)(Bb + kk * 32);
    short8 b1 = *(const short8*)(Bb + 16 * 256 + kk * 32);
    acc[0][0] = __builtin_amdgcn_mfma_f32_16x16x32_bf16(a0, b0, acc[0][0], 0, 0, 0);
    acc[0][1] = __builtin_amdgcn_mfma_f32_16x16x32_bf16(a0, b1, acc[0][1], 0, 0, 0);
    acc[1][0] = __builtin_amdgcn_mfma_f32_16x16x32_bf16(a1, b0, acc[1][0], 0, 0, 0);
    acc[1][1] = __builtin_amdgcn_mfma_f32_16x16x32_bf16(a1, b1, acc[1][1], 0, 0, 0);
  }

#pragma unroll
  for (int nt = 0; nt < 2; ++nt) {
    int col = bn + wn + nt * 16 + l16;
    float bv = bias[col] + ((col >= 512 && col < 768) ? 1.0f : 0.0f);
    int gate = col >> 8, jj = col & 255, qtc = jj >> 6, jl = jj & 63;
    int srow = qtc * 256 + gate * 64 + jl;
#pragma unroll
    for (int mt = 0; mt < 2; ++mt) {
#pragma unroll
      for (int r = 0; r < 4; ++r) {
        int row = bm + wm + mt * 16 + q * 4 + r;   // m = b*4096 + t
        size_t gidx = ((size_t)(row & 4095) * 32 + (row >> 12)) * 1024 + srow;
        G[gidx] = __float2half_rn(acc[mt][nt][r] + bv);
      }
    }
  }
}

// ---------------- recurrent scan (MFMA, 8 blocks x 256 thr) ----------------
// block bid: g = bid&1 (batch group of 16), qt = bid>>1 (j quarter, 64 j's).
// Wave w owns j-window [w*16, w*16+16): 4 gate Mtiles x 8 Ktiles = 32 MFMA/step.
// Lane (l16 = batch, q): C rows q*4+r -> j = w*16+q*4+r, col l16 = batch.
__global__ __launch_bounds__(256, 1) void k_scan(const _Float16* __restrict__ WhA,
                                                 const __half* __restrict__ G,
                                                 unsigned long long* __restrict__ hx,
                                                 int* __restrict__ ctr,
                                                 float* __restrict__ hfin) {
  __shared__ __align__(16) _Float16 Hl[16 * 64];   // local h slice [b][jl], XOR-swizzled

  const int tid = threadIdx.x;
  const int lane = tid & 63;
  const int w = tid >> 6;          // wave 0..3
  const int l16 = lane & 15;       // batch within group
  const int q = lane >> 4;         // 0..3
  const int bid = blockIdx.x;
  const int g = bid & 1;
  const int qt = bid >> 1;
  const int jl0 = w * 16 + q * 4;  // lane's j-local base (C-layout rows)

  // ---- A fragments: A[gate][kt], row = qt*256 + gate*64 + w*16 + l16 ----
  half8 A[4][8];
  {
    const _Float16* base = WhA + (size_t)(qt * 256 + w * 16 + l16) * 256 + q * 8;
#pragma unroll
    for (int gate = 0; gate < 4; ++gate)
#pragma unroll
      for (int kt = 0; kt < 8; ++kt)
        A[gate][kt] = *(const half8*)(base + (size_t)gate * 64 * 256 + kt * 32);
  }

  f32x4 acc[4] = {};               // one per gate (i,g,f,o)
  float cst[4] = {0.f, 0.f, 0.f, 0.f};
  unsigned long long rBv[8][2];    // remote B-frags by global Ktile (local slots unused)

  const unsigned short* Gu = (const unsigned short*)G;
  const size_t grow = (size_t)(g * 16 + l16);
  // gx address for (s, gate): ((s*32 + b)*1024 + qt*256 + gate*64 + jl0)
  uint2 gxn[4];
#pragma unroll
  for (int gate = 0; gate < 4; ++gate)
    gxn[gate] = *(const uint2*)(Gu + grow * 1024 + (size_t)(qt * 256 + gate * 64 + jl0));

  const int hxb = ((g * 4 + qt) * 16 + l16) * 16;  // write base (ull idx, within buf)

  for (int s = 0; s < T_STEPS; ++s) {
    if (s > 0) {
      // H_lds writes (h_s) from prev iter -> visible to all waves; remote loads stay in flight
      asm volatile("s_waitcnt lgkmcnt(0)\n\ts_barrier" ::: "memory");
#pragma unroll
      for (int kt = 0; kt < 8; ++kt) {
        half8 B;
        if ((kt >> 1) == qt) {     // wave-uniform branch: local slice from LDS
          int boff = (l16 * 128 + (kt & 1) * 64 + q * 16) ^ ((l16 & 7) << 4);
          B = *(const half8*)((const char*)Hl + boff);
        } else {                   // remote slice, loaded at end of prev iter
          ull2 t; t.x = rBv[kt][0]; t.y = rBv[kt][1];
          B = __builtin_bit_cast(half8, t);
        }
#pragma unroll
        for (int gate = 0; gate < 4; ++gate)
          acc[gate] = __builtin_amdgcn_mfma_f32_16x16x32_f16(A[gate][kt], B, acc[gate], 0, 0, 0);
      }
    }

    // ---- epilogue: gates = acc + gx ; nonlinearity ; h (4 values per lane) ----
    float h4[4];
#pragma unroll
    for (int r = 0; r < 4; ++r) {
      unsigned int wi = (r & 2) ? gxn[0].y : gxn[0].x;
      unsigned int wg = (r & 2) ? gxn[1].y : gxn[1].x;
      unsigned int wf = (r & 2) ? gxn[2].y : gxn[2].x;
      unsigned int wo = (r & 2) ? gxn[3].y : gxn[3].x;
      int sh = (r & 1) * 16;
      float gi = acc[0][r] + (float)__builtin_bit_cast(_Float16, (unsigned short)(wi >> sh));
      float gg = acc[1][r] + (float)__builtin_bit_cast(_Float16, (unsigned short)(wg >> sh));
      float gf = acc[2][r] + (float)__builtin_bit_cast(_Float16, (unsigned short)(wf >> sh));
      float go = acc[3][r] + (float)__builtin_bit_cast(_Float16, (unsigned short)(wo >> sh));
      float si = 1.0f / (1.0f + __expf(-gi));
      float sf = 1.0f / (1.0f + __expf(-gf));
      float so = 1.0f / (1.0f + __expf(-go));
      float eg = __expf(2.0f * gg);
      float tg = 1.0f - 2.0f / (eg + 1.0f);
      cst[r] = sf * cst[r] + si * tg;
      float ec = __expf(2.0f * cst[r]);
      float tc = 1.0f - 2.0f / (ec + 1.0f);
      h4[r] = so * tc;
    }

    if (s == T_STEPS - 1) {
      float4 hv; hv.x = h4[0]; hv.y = h4[1]; hv.z = h4[2]; hv.w = h4[3];
      *(float4*)(hfin + grow * 256 + qt * 64 + jl0) = hv;
    } else {
      // pack h_{s+1} -> 4 f16
      unsigned long long hp =
          (unsigned long long)__builtin_bit_cast(unsigned short, (_Float16)h4[0]) |
          ((unsigned long long)__builtin_bit_cast(unsigned short, (_Float16)h4[1]) << 16) |
          ((unsigned long long)__builtin_bit_cast(unsigned short, (_Float16)h4[2]) << 32) |
          ((unsigned long long)__builtin_bit_cast(unsigned short, (_Float16)h4[3]) << 48);

      // all waves done reading h_s from LDS before overwrite
      asm volatile("s_waitcnt lgkmcnt(0)\n\ts_barrier" ::: "memory");
      int woff = (l16 * 128 + jl0 * 2) ^ ((l16 & 7) << 4);
      *(unsigned long long*)((char*)Hl + woff) = hp;           // ds_write_b64

      const int buf = (s + 1) & 1;                             // step-parity double buffer
      __hip_atomic_store(hx + buf * 2048 + hxb + (jl0 >> 2), hp,
                         __ATOMIC_RELAXED, __HIP_MEMORY_SCOPE_AGENT);
      if (lane == 0)   // per-wave release: orders this wave's hx store before the count
        __hip_atomic_fetch_add(ctr + bid, 1, __ATOMIC_RELEASE, __HIP_MEMORY_SCOPE_AGENT);

      // prefetch gx for s+1 (independent of exchange)
#pragma unroll
      for (int gate = 0; gate < 4; ++gate)
        gxn[gate] = *(const uint2*)(Gu + ((size_t)(s + 1) * 32 + grow) * 1024 +
                                    (size_t)(qt * 256 + gate * 64 + jl0));
#pragma unroll
      for (int gate = 0; gate < 4; ++gate) acc[gate] = f32x4{0.f, 0.f, 0.f, 0.f};

      // wait for partners' h_{s+1} (4 wave-posts each per step)
      const int need = 4 * (s + 1);
#pragma unroll
      for (int rr = 0; rr < 4; ++rr) {
        if (rr == qt) continue;
        const int pb = rr * 2 + g;
        while (__hip_atomic_load(ctr + pb, __ATOMIC_ACQUIRE, __HIP_MEMORY_SCOPE_AGENT) < need) {}
      }
      // issue remote B-frag loads for s+1 (consumed after next barrier)
#pragma unroll
      for (int kt = 0; kt < 8; ++kt) {
        if ((kt >> 1) == qt) continue;
        size_t bi = (size_t)buf * 2048 + ((g * 4 + (kt >> 1)) * 16 + l16) * 16 +
                    (kt & 1) * 8 + q * 2;
        rBv[kt][0] = __hip_atomic_load(hx + bi, __ATOMIC_RELAXED, __HIP_MEMORY_SCOPE_AGENT);
        rBv[kt][1] = __hip_atomic_load(hx + bi + 1, __ATOMIC_RELAXED, __HIP_MEMORY_SCOPE_AGENT);
      }
    }
  }
}

// ---------------- head: out = (h@Wfc+bfc)@Wout+bout ----------------
__global__ void k_head(const float* __restrict__ hfin, const float* __restrict__ Wfc,
                       const float* __restrict__ bfc, const float* __restrict__ Wout,
                       const float* __restrict__ bout, float* __restrict__ out) {
  __shared__ float hs[256];
  __shared__ float fcs[256];
  int b = blockIdx.x, j = threadIdx.x;
  hs[j] = hfin[b * 256 + j];
  __syncthreads();
  float acc = bfc[j];
#pragma unroll 8
  for (int k = 0; k < 256; ++k) acc += hs[k] * Wfc[k * 256 + j];
  fcs[j] = acc;
  __syncthreads();
  if (j < 24) {
    float a2 = bout[j];
#pragma unroll 8
    for (int k = 0; k < 256; ++k) a2 += fcs[k] * Wout[k * 24 + j];
    out[b * 24 + j] = a2;
  }
}

extern "C" void kernel_launch(void* const* d_in, const int* in_sizes, int n_in,
                              void* d_out, int out_size, void* d_ws, size_t ws_size,
                              hipStream_t stream) {
  const float* x    = (const float*)d_in[0];
  const float* Wl   = (const float*)d_in[1];
  const float* bl   = (const float*)d_in[2];
  const float* Wfc  = (const float*)d_in[3];
  const float* bfc  = (const float*)d_in[4];
  const float* Wout = (const float*)d_in[5];
  const float* bout = (const float*)d_in[6];
  float* out = (float*)d_out;

  char* ws = (char*)d_ws;
  // ws layout (bytes), total ~321 MB
  unsigned short* xbf = (unsigned short*)ws;                    //  67108864  x as bf16
  unsigned short* WxT = (unsigned short*)(ws + 67108864);       //    524288  Wx^T bf16 [1024][256]
  _Float16*       WhA = (_Float16*)(ws + 67633152);             //    524288  Wh f16 [1024 srow][256 k]
  __half*         G   = (__half*)(ws + 68157440);               // 268435456  gates_x f16 [T][32][1024]
  float*          hfin= (float*)(ws + 336592896);               //     32768  final h f32
  // scan-time only (aliases xbf region, which is dead after xproj):
  unsigned long long* hx = (unsigned long long*)ws;             //  32768  h exchange, 2 bufs
  int* ctr = (int*)(ws + 32768);                                //  32  per-block wave counters

  k_prep_x<<<32768, 256, 0, stream>>>((const float4*)x, xbf, 8388608);
  k_prep_w<<<2048, 256, 0, stream>>>(Wl, WxT, WhA);
  dim3 gx(2048, 16, 1);
  k_xproj<<<gx, 256, 0, stream>>>(xbf, WxT, bl, G);
  hipMemsetAsync(ws + 32768, 0, 64, stream);                    // reset ctr (graph-replay safe)
  k_scan<<<8, 256, 0, stream>>>(WhA, G, hx, ctr, hfin);
  k_head<<<32, 256, 0, stream>>>(hfin, Wfc, bfc, Wout, bout, out);
}

// Round 3
// 7005.330 us; speedup vs baseline: 4.7808x; 4.7808x over previous
//
#include <hip/hip_runtime.h>
#include <hip/hip_fp16.h>

// LSTM: B=32, T=4096, D=256, H=256, gates=1024 (i,g,f,o), HORIZON=24
// Pipeline: prep_x (f32->bf16) ; prep_w (Wx transpose->bf16, Wh pack->f16 pairs) ;
//           xproj MFMA GEMM -> gates_x f16 [B][T][1024] (bias + forget+1 folded) ;
//           scan: 32 blocks x 512 thr, launch_bounds(512,1) so W_h (114 pairs x 2 cols
//                 = 228 VGPRs) is TRULY register-resident (r0 capped at 128 -> spills);
//                 tail 14 pairs quad-packed in LDS ([i][tid] layout, conflict-free b128);
//                 h broadcast as 32 uniform ds_read_b128/wave ;
//           head: two tiny FCs.

#define T_STEPS 4096
#define BATCH 32
#define RPAIRS 114   // f16 row-pairs of W_h per column held in VGPRs
#define LPAIRS 14    // remaining pairs in LDS (RPAIRS+LPAIRS == 128)

typedef short short8 __attribute__((ext_vector_type(8)));
typedef float f32x4 __attribute__((ext_vector_type(4)));
typedef _Float16 half2_t __attribute__((ext_vector_type(2)));

__device__ inline unsigned short f32_to_bf16(float f) {
  unsigned int u = __builtin_bit_cast(unsigned int, f);
  u = u + 0x7fffu + ((u >> 16) & 1u);   // RNE
  return (unsigned short)(u >> 16);
}

__device__ inline float fdot2f(unsigned int w, unsigned int h, float acc) {
#if __has_builtin(__builtin_amdgcn_fdot2)
  return __builtin_amdgcn_fdot2(__builtin_bit_cast(half2_t, w),
                                __builtin_bit_cast(half2_t, h), acc, false);
#else
  half2_t a = __builtin_bit_cast(half2_t, w);
  half2_t b = __builtin_bit_cast(half2_t, h);
  acc += (float)a.x * (float)b.x;
  acc += (float)a.y * (float)b.y;
  return acc;
#endif
}

// ---------------- prep: x f32 -> bf16 ----------------
__global__ void k_prep_x(const float4* __restrict__ x, unsigned short* __restrict__ xbf, int n4) {
  int i = blockIdx.x * blockDim.x + threadIdx.x;
  if (i >= n4) return;
  float4 v = x[i];
  ushort4 o;
  o.x = f32_to_bf16(v.x); o.y = f32_to_bf16(v.y);
  o.z = f32_to_bf16(v.z); o.w = f32_to_bf16(v.w);
  ((ushort4*)xbf)[i] = o;
}

// ---------------- prep: weights ----------------
// WxT[n][k] = bf16(W_lstm[k][n]) for k<256  (pre-transposed so xproj B-frags are contiguous)
// Whp[p][c] = pack(f16(W_lstm[256+2p][c]), f16(W_lstm[257+2p][c]))  p in [0,128)
__global__ void k_prep_w(const float* __restrict__ W, unsigned short* __restrict__ WxT,
                         unsigned int* __restrict__ Whp) {
  int i = blockIdx.x * blockDim.x + threadIdx.x;
  if (i < 256 * 1024) {
    int n = i >> 8, k = i & 255;
    WxT[i] = f32_to_bf16(W[k * 1024 + n]);
  } else {
    int j = i - 256 * 1024;   // j in [0, 131072)
    int p = j >> 10, c = j & 1023;
    _Float16 lo = (_Float16)W[(256 + 2 * p) * 1024 + c];
    _Float16 hi = (_Float16)W[(257 + 2 * p) * 1024 + c];
    Whp[j] = (unsigned int)__builtin_bit_cast(unsigned short, lo) |
             ((unsigned int)__builtin_bit_cast(unsigned short, hi) << 16);
  }
}

// ---------------- xproj: gates_x = x @ Wx + b (+1 on f-gate) ----------------
// M=131072, N=1024, K=256. bf16 MFMA 16x16x32, 64x64 tile per 256-thr block, direct global loads.
__global__ __launch_bounds__(256) void k_xproj(const unsigned short* __restrict__ A,
                                               const unsigned short* __restrict__ BT,
                                               const float* __restrict__ bias,
                                               __half* __restrict__ G) {
  int bm = blockIdx.x * 64;
  int bn = blockIdx.y * 64;
  int lane = threadIdx.x & 63, wave = threadIdx.x >> 6;
  int wm = (wave & 1) * 32, wn = (wave >> 1) * 32;
  int q = lane >> 4, l16 = lane & 15;

  f32x4 acc[2][2] = {};
  const unsigned short* Ab = A + (size_t)(bm + wm + l16) * 256 + q * 8;
  const unsigned short* Bb = BT + (size_t)(bn + wn + l16) * 256 + q * 8;

#pragma unroll
  for (int kk = 0; kk < 8; ++kk) {
    short8 a0 = *(const short8*)(Ab + kk * 32);
    short8 a1 = *(const short8*)(Ab + 16 * 256 + kk * 32);
    short8 b0 = *(const short8*)(Bb + kk * 32);
    short8 b1 = *(const short8*)(Bb + 16 * 256 + kk * 32);
    acc[0][0] = __builtin_amdgcn_mfma_f32_16x16x32_bf16(a0, b0, acc[0][0], 0, 0, 0);
    acc[0][1] = __builtin_amdgcn_mfma_f32_16x16x32_bf16(a0, b1, acc[0][1], 0, 0, 0);
    acc[1][0] = __builtin_amdgcn_mfma_f32_16x16x32_bf16(a1, b0, acc[1][0], 0, 0, 0);
    acc[1][1] = __builtin_amdgcn_mfma_f32_16x16x32_bf16(a1, b1, acc[1][1], 0, 0, 0);
  }

#pragma unroll
  for (int nt = 0; nt < 2; ++nt) {
    int col = bn + wn + nt * 16 + l16;
    float bv = bias[col] + ((col >= 512 && col < 768) ? 1.0f : 0.0f);
#pragma unroll
    for (int mt = 0; mt < 2; ++mt) {
#pragma unroll
      for (int r = 0; r < 4; ++r) {
        int row = bm + wm + mt * 16 + q * 4 + r;
        G[(size_t)row * 1024 + col] = __float2half_rn(acc[mt][nt][r] + bv);
      }
    }
  }
}

// ---------------- recurrent scan ----------------
// 32 blocks (one per batch element) x 512 threads. Thread t owns gate cols 2t, 2t+1.
// launch_bounds(512,1): 256-VGPR cap -> wA/wB truly resident (r0's (512,2) forced 128 and spilled).
__global__ __launch_bounds__(512, 1) void k_scan(const unsigned int* __restrict__ Whp,
                                                 const __half* __restrict__ G,
                                                 float* __restrict__ hfin) {
  __shared__ __align__(16) unsigned int h2[128];        // h packed as f16 pairs
  __shared__ float gates[1024];
  __shared__ __align__(16) uint4 WLq4[7 * 512];         // quad-packed tail, [i][tid]

  int tid = threadIdx.x;
  int b = blockIdx.x;
  int cA = 2 * tid;

  // stage quad-packed tail: WLq4[i*512+tid] = {wA[114+2i], wB[114+2i], wA[115+2i], wB[115+2i]}
#pragma unroll
  for (int i = 0; i < 7; ++i) {
    int p = RPAIRS + 2 * i;
    uint2 u = *(const uint2*)(Whp + (size_t)p * 1024 + cA);
    uint2 v = *(const uint2*)(Whp + (size_t)(p + 1) * 1024 + cA);
    WLq4[i * 512 + tid] = uint4{u.x, u.y, v.x, v.y};
  }

  // register-resident W_h (114 pairs for each of the 2 adjacent columns)
  unsigned int wA[RPAIRS], wB[RPAIRS];
#pragma unroll
  for (int p = 0; p < RPAIRS; ++p) {
    uint2 w = *(const uint2*)(Whp + p * 1024 + cA);
    wA[p] = w.x; wB[p] = w.y;
  }
  if (tid < 128) h2[tid] = 0u;   // h0 = 0
  float c_state = 0.0f;

  const unsigned short* gp = (const unsigned short*)(G + (size_t)b * T_STEPS * 1024);
  unsigned int gx_next = *(const unsigned int*)(gp + cA);   // step 0, cols 2t,2t+1
  __syncthreads();

  const uint4* h2q = (const uint4*)h2;

  for (int step = 0; step < T_STEPS; ++step) {
    unsigned int gx_cur = gx_next;
    if (step + 1 < T_STEPS)
      gx_next = *(const unsigned int*)(gp + (size_t)(step + 1) * 1024 + cA);

    half2_t gxh = __builtin_bit_cast(half2_t, gx_cur);
    float accA0 = (float)gxh.x, accB0 = (float)gxh.y;
    float accA1 = 0.0f, accB1 = 0.0f;

    // chunks 0..27: pairs 0..111, weights in VGPR, h via uniform b128 broadcast
#pragma unroll
    for (int ch = 0; ch < 28; ++ch) {
      uint4 hh = h2q[ch];
      accA0 = fdot2f(wA[ch * 4 + 0], hh.x, accA0); accB0 = fdot2f(wB[ch * 4 + 0], hh.x, accB0);
      accA1 = fdot2f(wA[ch * 4 + 1], hh.y, accA1); accB1 = fdot2f(wB[ch * 4 + 1], hh.y, accB1);
      accA0 = fdot2f(wA[ch * 4 + 2], hh.z, accA0); accB0 = fdot2f(wB[ch * 4 + 2], hh.z, accB0);
      accA1 = fdot2f(wA[ch * 4 + 3], hh.w, accA1); accB1 = fdot2f(wB[ch * 4 + 3], hh.w, accB1);
    }
    { // chunk 28: pairs 112,113 (VGPR) + 114,115 (WLq4[0])
      uint4 hh = h2q[28];
      uint4 q0 = WLq4[0 * 512 + tid];
      accA0 = fdot2f(wA[112], hh.x, accA0); accB0 = fdot2f(wB[112], hh.x, accB0);
      accA1 = fdot2f(wA[113], hh.y, accA1); accB1 = fdot2f(wB[113], hh.y, accB1);
      accA0 = fdot2f(q0.x, hh.z, accA0);    accB0 = fdot2f(q0.y, hh.z, accB0);
      accA1 = fdot2f(q0.z, hh.w, accA1);    accB1 = fdot2f(q0.w, hh.w, accB1);
    }
    // chunks 29..31: pairs 116..127 via WLq4[1..6] (per-lane b128, conflict-free layout)
#pragma unroll
    for (int ch = 0; ch < 3; ++ch) {
      uint4 hh = h2q[29 + ch];
      uint4 q0 = WLq4[(1 + 2 * ch) * 512 + tid];
      uint4 q1 = WLq4[(2 + 2 * ch) * 512 + tid];
      accA0 = fdot2f(q0.x, hh.x, accA0); accB0 = fdot2f(q0.y, hh.x, accB0);
      accA1 = fdot2f(q0.z, hh.y, accA1); accB1 = fdot2f(q0.w, hh.y, accB1);
      accA0 = fdot2f(q1.x, hh.z, accA0); accB0 = fdot2f(q1.y, hh.z, accB0);
      accA1 = fdot2f(q1.z, hh.w, accA1); accB1 = fdot2f(q1.w, hh.w, accB1);
    }

    *(float2*)(gates + cA) = float2{accA0 + accA1, accB0 + accB1};
    __syncthreads();

    if (tid < 256) {
      float gi = gates[tid];
      float gg = gates[tid + 256];
      float gf = gates[tid + 512];   // +1 already folded in
      float go = gates[tid + 768];
      float si = 1.0f / (1.0f + __expf(-gi));
      float sf = 1.0f / (1.0f + __expf(-gf));
      float so = 1.0f / (1.0f + __expf(-go));
      float eg = __expf(2.0f * gg);
      float tg = 1.0f - 2.0f / (eg + 1.0f);    // tanh, overflow-safe
      c_state = sf * c_state + si * tg;
      float ec = __expf(2.0f * c_state);
      float tc = 1.0f - 2.0f / (ec + 1.0f);
      float h = so * tc;
      ((__half*)h2)[tid] = __float2half_rn(h);
      if (step == T_STEPS - 1) hfin[b * 256 + tid] = h;
    }
    __syncthreads();
  }
}

// ---------------- head: out = (h@Wfc+bfc)@Wout+bout ----------------
__global__ void k_head(const float* __restrict__ hfin, const float* __restrict__ Wfc,
                       const float* __restrict__ bfc, const float* __restrict__ Wout,
                       const float* __restrict__ bout, float* __restrict__ out) {
  __shared__ float hs[256];
  __shared__ float fcs[256];
  int b = blockIdx.x, j = threadIdx.x;
  hs[j] = hfin[b * 256 + j];
  __syncthreads();
  float acc = bfc[j];
#pragma unroll 8
  for (int k = 0; k < 256; ++k) acc += hs[k] * Wfc[k * 256 + j];
  fcs[j] = acc;
  __syncthreads();
  if (j < 24) {
    float a2 = bout[j];
#pragma unroll 8
    for (int k = 0; k < 256; ++k) a2 += fcs[k] * Wout[k * 24 + j];
    out[b * 24 + j] = a2;
  }
}

extern "C" void kernel_launch(void* const* d_in, const int* in_sizes, int n_in,
                              void* d_out, int out_size, void* d_ws, size_t ws_size,
                              hipStream_t stream) {
  const float* x    = (const float*)d_in[0];
  const float* Wl   = (const float*)d_in[1];
  const float* bl   = (const float*)d_in[2];
  const float* Wfc  = (const float*)d_in[3];
  const float* bfc  = (const float*)d_in[4];
  const float* Wout = (const float*)d_in[5];
  const float* bout = (const float*)d_in[6];
  float* out = (float*)d_out;

  char* ws = (char*)d_ws;
  // ws layout (bytes), total ~321 MB
  unsigned short* xbf = (unsigned short*)ws;                    //  67108864  x as bf16
  unsigned short* WxT = (unsigned short*)(ws + 67108864);       //    524288  Wx^T bf16 [1024][256]
  unsigned int*   Whp = (unsigned int*)(ws + 67633152);         //    524288  Wh f16 pairs [128][1024]
  __half*         G   = (__half*)(ws + 68157440);               // 268435456  gates_x f16 [B][T][1024]
  float*          hfin= (float*)(ws + 336592896);               //     32768  final h f32

  k_prep_x<<<32768, 256, 0, stream>>>((const float4*)x, xbf, 8388608);
  k_prep_w<<<1536, 256, 0, stream>>>(Wl, WxT, Whp);
  dim3 gx(2048, 16, 1);
  k_xproj<<<gx, 256, 0, stream>>>(xbf, WxT, bl, G);
  k_scan<<<32, 512, 0, stream>>>(Whp, G, hfin);
  k_head<<<32, 256, 0, stream>>>(hfin, Wfc, bfc, Wout, bout, out);
}